// Round 1
// baseline (156.098 us; speedup 1.0000x reference)
//
#include <hip/hip_runtime.h>

typedef __attribute__((ext_vector_type(8))) short bf16x8;
typedef __attribute__((ext_vector_type(4))) float f32x4;
typedef unsigned int u32;
typedef unsigned short u16;
typedef unsigned long long u64;

#define NSEQ  4096
#define DD    64
#define NFREQ 32
#define NEG   3.0e4f
// log2(10000)/32 : inv_freq[i] = 2^(-i * L32)
#define L32   0.4152410118609203f

// (cos,sin)(pos * theta_f); 1 MB, block-invariant, filled per launch.
__device__ float2 g_tab[NSEQ * NFREQ];

__global__ __launch_bounds__(512) void rope_tab() {
    const int i = blockIdx.x * 512 + threadIdx.x;   // 256 blocks x 512 = 4096*32
    const int pos = i >> 5, fi = i & 31;
    const float th = exp2f(-(float)fi * L32);
    float s, c;
    sincosf((float)pos * th, &s, &c);
    g_tab[i] = make_float2(c, s);
}

// native packed f32->bf16 (RNE), 1 instr per 2 values (T12 primitive)
__device__ __forceinline__ u32 pkbf(float lo, float hi) {
    u32 r;
    asm("v_cvt_pk_bf16_f32 %0, %1, %2" : "=v"(r) : "v"(lo), "v"(hi));
    return r;
}

// one block = one (b*h, window): 128 queries x 256 keys, 8 waves x 16 queries.
// fp32 global I/O; bf16 only for MFMA operands. S^T = K*Q^T (softmax = 2
// shuffles). Single-pass K staging, ONE barrier. All LDS tiles XOR-swizzled
// at 16B-chunk granularity so b128 fragment reads are bank-uniform.
__global__ __launch_bounds__(512, 4) void lattn(
    const float* __restrict__ Q, const float* __restrict__ K,
    const float* __restrict__ V, const int* __restrict__ M,
    float* __restrict__ O)
{
    // chunk c (16B) of row r stored at chunk c ^ swz(r)
    __shared__ __align__(16) u16 Kb[256 * 64];  // [key][dim], swz = r&7       32768 B
    __shared__ __align__(16) u16 Vt[64 * 256];  // [dim][key], swz=(d^(d>>3))&7 32768 B
    __shared__ __align__(16) u16 Ps[8][512];    // per-wave P scratch, swz=m&3   8192 B
                                                // total 73728 B -> 2 blocks/CU

    const int w = blockIdx.x, bh = blockIdx.y, batch = bh >> 2;  // H = 4
    const int tid = threadIdx.x, lane = tid & 63, wv = tid >> 6;
    const int kbase = w * 128 - 128;
    const int m_ = lane & 15, qd = lane >> 4;
    const int rb = wv * 16;
    const int tq = w * 128 + rb + m_;          // this lane's query position

    // validity bits for 256 keys (pad & bin-mask), registers only
    u64 vb[4];
    #pragma unroll
    for (int i = 0; i < 4; ++i) {
        int gk = kbase + i * 64 + lane;
        int mv = (gk >= 0) ? M[batch * NSEQ + gk] : 0;
        vb[i] = __ballot(mv != 0);
    }

    // ---- stage V^T: thread = (key-pair kp, dim-quarter qt); packed b32 writes ----
    {
        const int kp = tid >> 2, qt = tid & 3;
        const int gk0 = kbase + 2 * kp;
        float v0[16] __attribute__((aligned(16)));
        float v1[16] __attribute__((aligned(16)));
        if (gk0 >= 0) {
            const float* vr = V + (size_t)(bh * NSEQ + gk0) * DD + qt * 16;
            #pragma unroll
            for (int i = 0; i < 4; ++i) {
                *(float4*)&v0[i * 4] = *(const float4*)(vr + i * 4);
                *(float4*)&v1[i * 4] = *(const float4*)(vr + DD + i * 4);
            }
        } else {
            #pragma unroll
            for (int i = 0; i < 16; ++i) { v0[i] = 0.f; v1[i] = 0.f; }
        }
        char* vtb = (char*)Vt + (kp & 3) * 4;   // byte within 16B chunk
        const u32 c0 = (u32)(kp >> 2);          // logical chunk = col/8
        #pragma unroll
        for (int i = 0; i < 16; ++i) {
            const int d = qt * 16 + i;
            const u32 swz = (u32)((d ^ (d >> 3)) & 7);
            *(u32*)(vtb + d * 512 + ((c0 ^ swz) << 4)) = pkbf(v0[i], v1[i]);
        }
    }

    // ---- stage K, all 256 keys in one pass: thread = (key r, dim-half q2) ----
    // thread owns dims [f0,f0+16) U [f0+32,f0+48): closed under rotate_half.
    {
        const int r = tid >> 1, q2 = tid & 1, f0 = q2 * 16;
        const int gk = kbase + r;
        u32 ol[8] __attribute__((aligned(16)));
        u32 oh[8] __attribute__((aligned(16)));
        if (gk >= 0) {
            const float* kr = K + (size_t)(bh * NSEQ + gk) * DD + f0;
            float a[16] __attribute__((aligned(16)));
            float b[16] __attribute__((aligned(16)));
            #pragma unroll
            for (int i = 0; i < 4; ++i) {
                *(float4*)&a[i * 4] = *(const float4*)(kr + i * 4);
                *(float4*)&b[i * 4] = *(const float4*)(kr + 32 + i * 4);
            }
            float2 cs[16] __attribute__((aligned(16)));
            const float2* tp = g_tab + gk * NFREQ + f0;
            #pragma unroll
            for (int i = 0; i < 8; ++i)
                *(float4*)&cs[i * 2] = *(const float4*)(tp + i * 2);
            #pragma unroll
            for (int j = 0; j < 8; ++j) {
                float l0 = a[2*j]   * cs[2*j].x   - b[2*j]   * cs[2*j].y;
                float l1 = a[2*j+1] * cs[2*j+1].x - b[2*j+1] * cs[2*j+1].y;
                float h0 = b[2*j]   * cs[2*j].x   + a[2*j]   * cs[2*j].y;
                float h1 = b[2*j+1] * cs[2*j+1].x + a[2*j+1] * cs[2*j+1].y;
                ol[j] = pkbf(l0, l1);
                oh[j] = pkbf(h0, h1);
            }
        } else {
            #pragma unroll
            for (int j = 0; j < 8; ++j) { ol[j] = 0u; oh[j] = 0u; }
        }
        char* kb = (char*)Kb + r * 128;
        const u32 cb = ((u32)(2 * q2) ^ (u32)(r & 7)) << 4;  // swizzled base chunk
        *(uint4*)(kb + (cb ^ 0u))  = *(uint4*)&ol[0];   // cols f0..f0+7
        *(uint4*)(kb + (cb ^ 16u)) = *(uint4*)&ol[4];   // cols f0+8..f0+15
        *(uint4*)(kb + (cb ^ 64u)) = *(uint4*)&oh[0];   // cols f0+32..f0+39
        *(uint4*)(kb + (cb ^ 80u)) = *(uint4*)&oh[4];   // cols f0+40..f0+47
    }

    // ---- Q fragments: RoPE from global LUT; 1/8 scale folded in (exact) ----
    bf16x8 qf0, qf1;
    {
        const float* qr = Q + (size_t)(bh * NSEQ + tq) * DD + qd * 8;
        float ql[8]  __attribute__((aligned(16)));
        float qh_[8] __attribute__((aligned(16)));
        *(float4*)&ql[0]  = *(const float4*)(qr);
        *(float4*)&ql[4]  = *(const float4*)(qr + 4);
        *(float4*)&qh_[0] = *(const float4*)(qr + 32);
        *(float4*)&qh_[4] = *(const float4*)(qr + 36);
        float2 cs[8] __attribute__((aligned(16)));
        const float2* tp = g_tab + tq * NFREQ + qd * 8;
        #pragma unroll
        for (int i = 0; i < 4; ++i)
            *(float4*)&cs[i * 2] = *(const float4*)(tp + i * 2);
        u32 w0[4] __attribute__((aligned(16)));
        u32 w1[4] __attribute__((aligned(16)));
        #pragma unroll
        for (int j = 0; j < 4; ++j) {
            float c0 = cs[2*j].x   * 0.125f, s0 = cs[2*j].y   * 0.125f;
            float c1 = cs[2*j+1].x * 0.125f, s1 = cs[2*j+1].y * 0.125f;
            w0[j] = pkbf(ql[2*j]  * c0 - qh_[2*j]  * s0,
                         ql[2*j+1]* c1 - qh_[2*j+1]* s1);
            w1[j] = pkbf(qh_[2*j]  * c0 + ql[2*j]  * s0,
                         qh_[2*j+1]* c1 + ql[2*j+1]* s1);
        }
        qf0 = *(bf16x8*)w0;
        qf1 = *(bf16x8*)w1;
    }

    __syncthreads();                       // the ONLY barrier: staging complete

    // ---- S^T = K·Q^T over 16 key-tiles ----
    f32x4 acc[16];
    const f32x4 zf = {0.f, 0.f, 0.f, 0.f};
    {
        const u32 co = ((u32)(qd ^ (m_ & 7))) << 4;   // swizzled chunk, per-thread const
        const char* kb0 = (const char*)Kb + m_ * 128 + co;
        const char* kb1 = (const char*)Kb + m_ * 128 + (co ^ 64u);
        #pragma unroll
        for (int t = 0; t < 16; ++t) {
            bf16x8 kf0 = *(const bf16x8*)(kb0 + t * 2048);
            bf16x8 kf1 = *(const bf16x8*)(kb1 + t * 2048);
            f32x4 c0 = __builtin_amdgcn_mfma_f32_16x16x32_bf16(kf0, qf0, zf, 0, 0, 0);
            acc[t]   = __builtin_amdgcn_mfma_f32_16x16x32_bf16(kf1, qf1, c0, 0, 0, 0);
        }
    }

    // ---- mask + softmax (unnormalized P; 1/sum deferred to epilogue) ----
    // C/D layout: lane holds key nn = t*16 + qd*4 + r, query col m_
    const int lim = tq - kbase;                        // causal: nn <= lim
    float mx = -NEG;
    #pragma unroll
    for (int t = 0; t < 16; ++t)
        #pragma unroll
        for (int r = 0; r < 4; ++r) {
            int nn = t * 16 + qd * 4 + r;
            bool ok = (nn <= lim) && ((vb[t >> 2] >> (nn & 63)) & 1ull);
            float s = ok ? acc[t][r] : -NEG;           // scale already in Q
            acc[t][r] = s;
            mx = fmaxf(mx, s);
        }
    mx = fmaxf(mx, __shfl_xor(mx, 16));
    mx = fmaxf(mx, __shfl_xor(mx, 32));
    float sum = 0.f;
    #pragma unroll
    for (int t = 0; t < 16; ++t)
        #pragma unroll
        for (int r = 0; r < 4; ++r) {
            float p = __expf(acc[t][r] - mx);          // <= 0 argument, p in [0,1]
            acc[t][r] = p; sum += p;
        }

    // ---- O = P·V per 32-key chunk; P via wave-private swizzled LDS scratch ----
    f32x4 o[4] = {zf, zf, zf, zf};
    {
        const u32 wbase = (u32)(wv * 1024 + m_ * 64);
        const u32 ch0 = ((((u32)qd >> 1) ^ (u32)(m_ & 3)) << 4);
        char* pw0 = (char*)Ps + wbase + (qd & 1) * 8 + ch0;          // cols qd*4..+3
        char* pw1 = (char*)Ps + wbase + (qd & 1) * 8 + (ch0 ^ 32u);  // cols 16+qd*4..+3
        const char* pr = (const char*)Ps + wbase +
                         (((u32)qd ^ (u32)(m_ & 3)) << 4);           // cols qd*8..+7
        const char* vbase[4];
        u32 vxo[4];
        #pragma unroll
        for (int et = 0; et < 4; ++et) {
            const int d = et * 16 + m_;
            const u32 swz = (u32)((d ^ (d >> 3)) & 7);
            vbase[et] = (const char*)Vt + d * 512 + (((u32)qd ^ (swz & 3u)) << 4);
            vxo[et] = (swz >> 2) << 6;
        }
        #pragma unroll
        for (int kc = 0; kc < 8; ++kc) {
            u32 p0 = pkbf(acc[2*kc][0],   acc[2*kc][1]);
            u32 p1 = pkbf(acc[2*kc][2],   acc[2*kc][3]);
            u32 p2 = pkbf(acc[2*kc+1][0], acc[2*kc+1][1]);
            u32 p3 = pkbf(acc[2*kc+1][2], acc[2*kc+1][3]);
            *(uint2*)pw0 = make_uint2(p0, p1);
            *(uint2*)pw1 = make_uint2(p2, p3);
            __builtin_amdgcn_sched_barrier(0);         // keep read after writes
            bf16x8 pf = *(const bf16x8*)pr;
            __builtin_amdgcn_sched_barrier(0);         // keep next writes after read
            #pragma unroll
            for (int et = 0; et < 4; ++et) {
                bf16x8 vf = *(const bf16x8*)(vbase[et] + (((u32)(kc << 6)) ^ vxo[et]));
                o[et] = __builtin_amdgcn_mfma_f32_16x16x32_bf16(pf, vf, o[et], 0, 0, 0);
            }
        }
    }

    // ---- epilogue: normalize by 1/sum (per-query, fetched via shuffle) ----
    sum += __shfl_xor(sum, 16);
    sum += __shfl_xor(sum, 32);
    const float is = 1.f / sum;                        // sum >= 1 (self key valid)
    float isq[4];
    #pragma unroll
    for (int r = 0; r < 4; ++r) isq[r] = __shfl(is, qd * 4 + r);
    // C layout: lane holds out[query = rb + qd*4 + r][e = et*16 + m_]; fp32 out
    float* ob = O + (size_t)(bh * NSEQ + w * 128 + rb + qd * 4) * DD;
    #pragma unroll
    for (int r = 0; r < 4; ++r)
        #pragma unroll
        for (int et = 0; et < 4; ++et)
            ob[r * DD + et * 16 + m_] = o[et][r] * isq[r];
}

extern "C" void kernel_launch(void* const* d_in, const int* in_sizes, int n_in,
                              void* d_out, int out_size, void* d_ws, size_t ws_size,
                              hipStream_t stream) {
    const float* q = (const float*)d_in[0];
    const float* k = (const float*)d_in[1];
    const float* v = (const float*)d_in[2];
    const int*   m = (const int*)d_in[3];
    float* o = (float*)d_out;
    rope_tab<<<dim3(NSEQ * NFREQ / 512), 512, 0, stream>>>();
    dim3 grid(32, 32);   // x = window, y = b*h
    lattn<<<grid, 512, 0, stream>>>(q, k, v, m, o);
}